// Round 18
// baseline (14293.843 us; speedup 1.0000x reference)
//
#include <hip/hip_runtime.h>
#include <math.h>

#define ESN_B 16
#define ESN_T 2048
#define ESN_R 1024
#define ESN_IN 64
#define NBR (ESN_B * ESN_R)

// ---- workspace layout (float offsets) ----
#define OFF_WT_HH0 0                               // [1024][1024]  W_hh0^T
#define OFF_WT_IN1 (1024 * 1024)                   // [1024][1024]  W_in1^T
#define OFF_WT_HH1 (2 * 1024 * 1024)               // [1024][1024]  W_hh1^T
#define OFF_WT_IN0 (3 * 1024 * 1024)               // [1024][64]    W_in0^T
#define OFF_RT     (OFF_WT_IN0 + 1024 * 64)        // [64][2048]    readout^T
#define OFF_S0G    (OFF_RT + 64 * 2048)            // [2][16][1024] s0 double buffer
#define OFF_S1G    (OFF_S0G + 2 * NBR)             // [2][16][1024] s1 double buffer
#define OFF_FLAGS  (OFF_S1G + 2 * NBR)             // [4][64] u32 per-block flags

typedef float vfloat4 __attribute__((__vector_size__(16)));

// ---------------- transpose: dst[c][r] = src[r][c] ----------------
__global__ void __launch_bounds__(256) transpose_k(const float* __restrict__ src,
                                                   float* __restrict__ dst,
                                                   int rows, int cols) {
  __shared__ float tile[32][33];
  int bx = blockIdx.x * 32, by = blockIdx.y * 32;
  int tx = threadIdx.x, ty = threadIdx.y;  // 32 x 8
  #pragma unroll
  for (int i = ty; i < 32; i += 8) {
    int r = by + i, c = bx + tx;
    if (r < rows && c < cols) tile[i][tx] = src[(size_t)r * cols + c];
  }
  __syncthreads();
  #pragma unroll
  for (int i = ty; i < 32; i += 8) {
    int c = bx + i, r = by + tx;
    if (c < cols && r < rows) dst[(size_t)c * rows + r] = tile[tx][i];
  }
}

// ---------------- helpers ----------------
__device__ __forceinline__ float fast_tanh(float v) {
  float a = fabsf(v);
  float e = __expf(-2.0f * a);
  float t = __fdividef(1.0f - e, 1.0f + e);
  return copysignf(t, v);
}

__device__ __forceinline__ float dot4(float4 a, float4 b, float acc) {
  acc = fmaf(a.x, b.x, acc);
  acc = fmaf(a.y, b.y, acc);
  acc = fmaf(a.z, b.z, acc);
  acc = fmaf(a.w, b.w, acc);
  return acc;
}

__device__ __forceinline__ float wave_red64(float v) {
  #pragma unroll
  for (int off = 32; off > 0; off >>= 1) v += __shfl_xor(v, off, 64);
  return v;
}

// 4 independent 64-lane sums with 7 shuffles; lane l returns sum a_{l&3}
__device__ __forceinline__ float reduce4(float a0, float a1, float a2, float a3,
                                         bool lb0, bool lb1) {
  float uA = lb0 ? a0 : a1, kA = lb0 ? a1 : a0;
  float A = kA + __shfl_xor(uA, 1, 64);
  float uB = lb0 ? a2 : a3, kB = lb0 ? a3 : a2;
  float B = kB + __shfl_xor(uB, 1, 64);
  float uC = lb1 ? A : B, kC = lb1 ? B : A;
  float C = kC + __shfl_xor(uC, 2, 64);
  C += __shfl_xor(C, 4, 64);
  C += __shfl_xor(C, 8, 64);
  C += __shfl_xor(C, 16, 64);
  C += __shfl_xor(C, 32, 64);
  return C;
}

// device-scope (LLC-coherent) memory ops: bypass L1/L2, no cache invalidates
__device__ __forceinline__ void llc_store_f32x4(float* p, float4 v) {
  vfloat4 vv = {v.x, v.y, v.z, v.w};
  asm volatile("global_store_dwordx4 %0, %1, off sc1" :: "v"(p), "v"(vv) : "memory");
}
__device__ __forceinline__ void llc_store_u32(unsigned* p, unsigned v) {
  asm volatile("global_store_dword %0, %1, off sc1" :: "v"(p), "v"(v) : "memory");
}
__device__ __forceinline__ unsigned llc_load_u32(const unsigned* p) {
  unsigned f;
  asm volatile("global_load_dword %0, %1, off sc1\n\ts_waitcnt vmcnt(0)"
               : "=v"(f) : "v"(p) : "memory");
  return f;
}
__device__ __forceinline__ void vmcnt0() {
  asm volatile("s_waitcnt vmcnt(0)" ::: "memory");
}
__device__ __forceinline__ void barrier_lgkm() {
  asm volatile("s_waitcnt lgkmcnt(0)" ::: "memory");
  __builtin_amdgcn_s_barrier();
  asm volatile("" ::: "memory");
}

// ---------------- persistent fused scan (ring + source-gated poll) ----------
// 4 groups x 64 blocks x 512 threads (8 waves; 80.6KB LDS -> 1 block/CU).
// Merged L0+L1 compute (r15). s0l = 3-slot ring, s1l = 2-slot ring: staging(r)
// never overwrites what RO(r-1) reads -> NO pre-stage barrier. Poll is
// SOURCE-GATED: thread t stages cols [4t,4t+4) written by block (t&255)>>2,
// so it polls exactly that one flag; per wave = 16 flags = ONE 64B line
// (vs r16's 4 lines/wave -> that poll-traffic regression). Transitivity:
// a block's 512 threads collectively poll all 64 flags, so the syncB
// rendezvous preserves the overwrite-safety argument. 2 barriers/round.
// Publish stays coarse: wave0 gathers res and stores 2x 64B lines + 1 flag.
__global__ void __launch_bounds__(512, 2) esn_scan_kernel(
    const float* __restrict__ x,
    const float* __restrict__ b0,
    const float* __restrict__ b1,
    float* __restrict__ wsf,
    float* __restrict__ out) {
  __shared__ float s0l[3][4][1024];              // slot r%3
  __shared__ float s1l[2][4][1024];              // slot r&1
  __shared__ __align__(16) float res[2][4][20];  // stride 20: bank-spread

  const float* wtHH0 = wsf + OFF_WT_HH0;
  const float* wtIN1 = wsf + OFF_WT_IN1;
  const float* wtHH1 = wsf + OFF_WT_HH1;
  const float* wtIN0 = wsf + OFF_WT_IN0;
  const float* rt    = wsf + OFF_RT;
  float* s0g = wsf + OFF_S0G;
  float* s1g = wsf + OFF_S1G;
  unsigned* flags = (unsigned*)(wsf + OFF_FLAGS);

  const int tid = threadIdx.x;
  const int l = tid & 63;
  const int w = tid >> 6;            // wave 0..7
  const int bid = blockIdx.x;
  const int g = bid >> 6;            // group 0..3
  const int bg = bid & 63;           // block in group
  const int batch0 = g * 4;
  const int wg = bg * 8 + w;         // wave idx in group 0..511
  const int c0 = wg * 2;             // wave's first column (= bg*16 + w*2)
  const int wl2 = w * 2;             // block-local col base
  const bool doROw = (w >= 4);       // waves 4..7: readout (rbl=w-4, roc=bg)
  const int rbl = w - 4;             // readout local batch (RO waves)
  const int rb = batch0 + rbl;       // readout batch
  const int roc = bg;                // readout out-col
  unsigned* gflags = flags + g * 64; // [64 blocks]
  const unsigned* myfp = gflags + ((tid & 255) >> 2);  // this thread's source flag
  const bool lb0 = (l & 1) != 0;
  const bool lb1 = (l & 2) != 0;

  // ---- persistent per-lane weights as NAMED float4s (k = q*256 + l*4 + j) ----
  float4 wA0_0, wA0_1, wA0_2, wA0_3, wA1_0, wA1_1, wA1_2, wA1_3;
  float4 wB0_0, wB0_1, wB0_2, wB0_3, wB1_0, wB1_1, wB1_2, wB1_3;
  float4 wC0_0, wC0_1, wC0_2, wC0_3, wC1_0, wC1_1, wC1_2, wC1_3;
  float4 rd0, rd1, rd2, rd3, rd4, rd5, rd6, rd7;

#define LOADW(cc) { \
    const float* pA = wtHH0 + (size_t)(c0 + cc) * ESN_R + l * 4; \
    const float* pB = wtIN1 + (size_t)(c0 + cc) * ESN_R + l * 4; \
    const float* pC = wtHH1 + (size_t)(c0 + cc) * ESN_R + l * 4; \
    wA##cc##_0 = *(const float4*)(pA);       wA##cc##_1 = *(const float4*)(pA + 256); \
    wA##cc##_2 = *(const float4*)(pA + 512); wA##cc##_3 = *(const float4*)(pA + 768); \
    wB##cc##_0 = *(const float4*)(pB);       wB##cc##_1 = *(const float4*)(pB + 256); \
    wB##cc##_2 = *(const float4*)(pB + 512); wB##cc##_3 = *(const float4*)(pB + 768); \
    wC##cc##_0 = *(const float4*)(pC);       wC##cc##_1 = *(const float4*)(pC + 256); \
    wC##cc##_2 = *(const float4*)(pC + 512); wC##cc##_3 = *(const float4*)(pC + 768); \
  }
  LOADW(0) LOADW(1)
#undef LOADW

  rd0 = rd1 = rd2 = rd3 = rd4 = rd5 = rd6 = rd7 = make_float4(0.f, 0.f, 0.f, 0.f);
  if (doROw) {
    const float* pr = rt + (size_t)roc * 2048 + l * 4;
    rd0 = *(const float4*)(pr);        rd1 = *(const float4*)(pr + 256);
    rd2 = *(const float4*)(pr + 512);  rd3 = *(const float4*)(pr + 768);
    rd4 = *(const float4*)(pr + 1024); rd5 = *(const float4*)(pr + 1280);
    rd6 = *(const float4*)(pr + 1536); rd7 = *(const float4*)(pr + 1792);
  }
  const float wI0 = wtIN0[(size_t)(c0 + 0) * ESN_IN + l];
  const float wI1 = wtIN0[(size_t)(c0 + 1) * ESN_IN + l];
  float bsel = 0.f;
  if (l < 4) bsel = ((l < 2) ? b0 : b1)[c0 + (l & 1)];

  // ---- hoisted pointers (parity-specific, compile-time selected below) ----
  const float* sA0 = s0g + 0 * NBR + batch0 * ESN_R + tid * 4;  // s0 slot0
  const float* sA1 = s0g + 1 * NBR + batch0 * ESN_R + tid * 4;  // s0 slot1
  const float* sB0 = s1g + 0 * NBR + batch0 * ESN_R + tid * 4;
  const float* sB1 = s1g + 1 * NBR + batch0 * ESN_R + tid * 4;
  // wave0 gather-store: lanes 0-15 -> s0g, lanes 16-31 -> s1g
  float* gb = ((l < 16) ? s0g : s1g) +
              (batch0 + ((l >> 2) & 3)) * ESN_R + bg * 16 + (l & 3) * 4;
  float* gbA = gb;            // parity 0
  float* gbB = gb + NBR;      // parity 1
  const float* xbase = x + (size_t)batch0 * ESN_T * ESN_IN + l;

  // One round. S0S = r%3 (compile-time), PAR = r&1 (compile-time).
#define ESN_ROUND(S0S, PAR, rr)                                                \
  {                                                                            \
    const bool doL0 = ((rr) < ESN_T);                                          \
    const bool doL1 = ((rr) >= 1 && (rr) <= ESN_T);                            \
    const bool doRO = ((rr) >= 2 && (rr) < ESN_T + 2) && doROw;                \
    float xv0 = 0.f, xv1 = 0.f, xv2 = 0.f, xv3 = 0.f;                          \
    if (doL0) {                                                                \
      const float* xp = xbase + (size_t)(rr) * ESN_IN;                         \
      xv0 = xp[0 * ESN_T * ESN_IN];                                            \
      xv1 = xp[1 * ESN_T * ESN_IN];                                            \
      xv2 = xp[2 * ESN_T * ESN_IN];                                            \
      xv3 = xp[3 * ESN_T * ESN_IN];                                            \
    }                                                                          \
    if ((rr) > 0) { /* source-gated poll: one 64B flag line per wave */        \
      while (!__all(llc_load_u32(myfp) >= (unsigned)(rr))) {}                  \
    }                                                                          \
    const float* q0 = (PAR) ? sA0 : sA1; /* stage reads slot PAR^1 */          \
    const float* q1 = (PAR) ? sB0 : sB1;                                       \
    float4 t0, t1, u0, u1;                                                     \
    asm volatile(                                                              \
        "global_load_dwordx4 %0, %4, off sc1\n\t"                              \
        "global_load_dwordx4 %1, %5, off sc1\n\t"                              \
        "global_load_dwordx4 %2, %6, off sc1\n\t"                              \
        "global_load_dwordx4 %3, %7, off sc1\n\t"                              \
        "s_waitcnt vmcnt(0)"                                                   \
        : "=&v"(t0), "=&v"(t1), "=&v"(u0), "=&v"(u1)                           \
        : "v"(q0), "v"(q0 + 2048), "v"(q1), "v"(q1 + 2048)                     \
        : "memory");                                                           \
    {                                                                          \
      float* d0 = &s0l[S0S][0][0] + tid * 4;                                   \
      float* d1 = &s1l[PAR][0][0] + tid * 4;                                   \
      *(float4*)(d0)        = t0;                                              \
      *(float4*)(d0 + 2048) = t1;                                              \
      *(float4*)(d1)        = u0;                                              \
      *(float4*)(d1 + 2048) = u1;                                              \
    }                                                                          \
    barrier_lgkm(); /* syncB: s0l[S0S] + s1l[PAR] staged */                    \
    _Pragma("unroll")                                                          \
    for (int bb = 0; bb < 4; ++bb) {                                           \
      const float* hp = &s0l[S0S][bb][l * 4];                                  \
      float4 h0x = *(const float4*)(hp);                                       \
      float4 h1x = *(const float4*)(hp + 256);                                 \
      float4 h2x = *(const float4*)(hp + 512);                                 \
      float4 h3x = *(const float4*)(hp + 768);                                 \
      const float* gp = &s1l[PAR][bb][l * 4];                                  \
      float4 g0x = *(const float4*)(gp);                                       \
      float4 g1x = *(const float4*)(gp + 256);                                 \
      float4 g2x = *(const float4*)(gp + 512);                                 \
      float4 g3x = *(const float4*)(gp + 768);                                 \
      float xb = (bb == 0) ? xv0 : (bb == 1) ? xv1 : (bb == 2) ? xv2 : xv3;    \
      float a0 = xb * wI0, a1 = xb * wI1;                                      \
      a0 = dot4(wA0_0, h0x, a0); a0 = dot4(wA0_1, h1x, a0);                    \
      a0 = dot4(wA0_2, h2x, a0); a0 = dot4(wA0_3, h3x, a0);                    \
      a1 = dot4(wA1_0, h0x, a1); a1 = dot4(wA1_1, h1x, a1);                    \
      a1 = dot4(wA1_2, h2x, a1); a1 = dot4(wA1_3, h3x, a1);                    \
      float a2 = 0.f, a3 = 0.f;                                                \
      a2 = dot4(wB0_0, h0x, a2); a2 = dot4(wB0_1, h1x, a2);                    \
      a2 = dot4(wB0_2, h2x, a2); a2 = dot4(wB0_3, h3x, a2);                    \
      a2 = dot4(wC0_0, g0x, a2); a2 = dot4(wC0_1, g1x, a2);                    \
      a2 = dot4(wC0_2, g2x, a2); a2 = dot4(wC0_3, g3x, a2);                    \
      a3 = dot4(wB1_0, h0x, a3); a3 = dot4(wB1_1, h1x, a3);                    \
      a3 = dot4(wB1_2, h2x, a3); a3 = dot4(wB1_3, h3x, a3);                    \
      a3 = dot4(wC1_0, g0x, a3); a3 = dot4(wC1_1, g1x, a3);                    \
      a3 = dot4(wC1_2, g2x, a3); a3 = dot4(wC1_3, g3x, a3);                    \
      float C = reduce4(a0, a1, a2, a3, lb0, lb1);                             \
      if (l < 4) { /* lanes 0,1: L0 cols; lanes 2,3: L1 cols */                \
        const float* pbase = (l < 2) ? &s0l[S0S][bb][0] : &s1l[PAR][bb][0];    \
        float prev = pbase[c0 + (l & 1)];                                      \
        float nv = 0.5f * prev + 0.5f * fast_tanh(C + bsel);                   \
        bool wr = (l < 2) ? doL0 : doL1;                                       \
        if (wr) res[l >> 1][bb][wl2 + (l & 1)] = nv;                           \
      }                                                                        \
    }                                                                          \
    barrier_lgkm(); /* syncC: res ready */                                     \
    if (w == 0) {                                                              \
      if (l < 32 && ((l < 16) ? doL0 : doL1)) {                                \
        float4 v;                                                              \
        {                                                                      \
          const float* rp_ = &res[l >> 4][(l >> 2) & 3][(l & 3) * 4];          \
          v = *(const float4*)rp_;                                             \
        }                                                                      \
        llc_store_f32x4((PAR) ? gbB : gbA, v);                                 \
      }                                                                        \
      vmcnt0();                                                                \
      if (l == 0) llc_store_u32(&gflags[bg], (unsigned)((rr) + 1));            \
    }                                                                          \
    if (doRO) { /* reads s0l slot (S0S+2)%3 (staged last round) + s1l[PAR] */  \
      const float* sp = &s0l[(S0S + 2) % 3][rbl][l * 4];                       \
      const float* tp = &s1l[PAR][rbl][l * 4];                                 \
      float a = 0.f;                                                           \
      a = dot4(rd0, *(const float4*)(sp), a);                                  \
      a = dot4(rd1, *(const float4*)(sp + 256), a);                            \
      a = dot4(rd2, *(const float4*)(sp + 512), a);                            \
      a = dot4(rd3, *(const float4*)(sp + 768), a);                            \
      a = dot4(rd4, *(const float4*)(tp), a);                                  \
      a = dot4(rd5, *(const float4*)(tp + 256), a);                            \
      a = dot4(rd6, *(const float4*)(tp + 512), a);                            \
      a = dot4(rd7, *(const float4*)(tp + 768), a);                            \
      a = wave_red64(a);                                                       \
      if (l == 0) out[((size_t)rb * ESN_T + ((rr) - 2)) * ESN_IN + roc] = a;   \
    }                                                                          \
  }

  // 2052 rounds = 342 x 6 (period of (r%3, r&1)); rounds 2050-2051 are
  // poll+pub only (all do* guards false) — cheap, keeps flag protocol simple.
  for (int rp = 0; rp < 342; ++rp) {
    const int r0 = rp * 6;
    ESN_ROUND(0, 0, r0 + 0)
    ESN_ROUND(1, 1, r0 + 1)
    ESN_ROUND(2, 0, r0 + 2)
    ESN_ROUND(0, 1, r0 + 3)
    ESN_ROUND(1, 0, r0 + 4)
    ESN_ROUND(2, 1, r0 + 5)
  }
#undef ESN_ROUND
}

// ---------------- host launch ----------------
extern "C" void kernel_launch(void* const* d_in, const int* in_sizes, int n_in,
                              void* d_out, int out_size, void* d_ws, size_t ws_size,
                              hipStream_t stream) {
  (void)in_sizes; (void)n_in; (void)out_size; (void)ws_size;
  const float* x     = (const float*)d_in[0];
  const float* w_in0 = (const float*)d_in[1];
  const float* w_hh0 = (const float*)d_in[2];
  const float* b0    = (const float*)d_in[3];
  const float* w_in1 = (const float*)d_in[4];
  const float* w_hh1 = (const float*)d_in[5];
  const float* b1    = (const float*)d_in[6];
  const float* rdo   = (const float*)d_in[7];
  float* out = (float*)d_out;
  float* wsf = (float*)d_ws;

  dim3 tb(32, 8);
  transpose_k<<<dim3(32, 32), tb, 0, stream>>>(w_hh0, wsf + OFF_WT_HH0, 1024, 1024);
  transpose_k<<<dim3(32, 32), tb, 0, stream>>>(w_in1, wsf + OFF_WT_IN1, 1024, 1024);
  transpose_k<<<dim3(32, 32), tb, 0, stream>>>(w_hh1, wsf + OFF_WT_HH1, 1024, 1024);
  transpose_k<<<dim3(32, 2),  tb, 0, stream>>>(w_in0, wsf + OFF_WT_IN0, 64, 1024);
  transpose_k<<<dim3(2, 64),  tb, 0, stream>>>(rdo,   wsf + OFF_RT, 2048, 64);

  // zero the state slots read before first writes:
  // r=0 stages s0g[1] and s1g[1]; r=1 stages s1g[0] (no s1 store at r=0)
  (void)hipMemsetAsync(wsf + OFF_S0G + NBR, 0, NBR * sizeof(float), stream);
  (void)hipMemsetAsync(wsf + OFF_S1G, 0, 2 * NBR * sizeof(float), stream);
  (void)hipMemsetAsync(wsf + OFF_FLAGS, 0, 4 * 64 * sizeof(unsigned), stream);

  // 80.6KB static LDS -> 1 block/CU; 8 waves -> 2/SIMD
  esn_scan_kernel<<<dim3(256), dim3(512), 0, stream>>>(x, b0, b1, wsf, out);
}

// Round 19
// 11423.945 us; speedup vs baseline: 1.2512x; 1.2512x over previous
//
#include <hip/hip_runtime.h>
#include <math.h>

#define ESN_B 16
#define ESN_T 2048
#define ESN_R 1024
#define ESN_IN 64
#define NBR (ESN_B * ESN_R)

// ---- workspace layout (float offsets) ----
#define OFF_WT_HH0 0                               // [1024][1024]  W_hh0^T
#define OFF_WT_IN1 (1024 * 1024)                   // [1024][1024]  W_in1^T
#define OFF_WT_HH1 (2 * 1024 * 1024)               // [1024][1024]  W_hh1^T
#define OFF_WT_IN0 (3 * 1024 * 1024)               // [1024][64]    W_in0^T
#define OFF_RT     (OFF_WT_IN0 + 1024 * 64)        // [64][2048]    readout^T
#define OFF_S0G    (OFF_RT + 64 * 2048)            // [2][16][1024] s0 double buffer
#define OFF_S1G    (OFF_S0G + 2 * NBR)             // [2][16][1024] s1 double buffer
#define OFF_FLAGS  (OFF_S1G + 2 * NBR)             // [4][64] u32 per-block flags

typedef float vfloat4 __attribute__((__vector_size__(16)));

// ---------------- transpose: dst[c][r] = src[r][c] ----------------
__global__ void __launch_bounds__(256) transpose_k(const float* __restrict__ src,
                                                   float* __restrict__ dst,
                                                   int rows, int cols) {
  __shared__ float tile[32][33];
  int bx = blockIdx.x * 32, by = blockIdx.y * 32;
  int tx = threadIdx.x, ty = threadIdx.y;  // 32 x 8
  #pragma unroll
  for (int i = ty; i < 32; i += 8) {
    int r = by + i, c = bx + tx;
    if (r < rows && c < cols) tile[i][tx] = src[(size_t)r * cols + c];
  }
  __syncthreads();
  #pragma unroll
  for (int i = ty; i < 32; i += 8) {
    int c = bx + i, r = by + tx;
    if (c < cols && r < rows) dst[(size_t)c * rows + r] = tile[tx][i];
  }
}

// ---------------- helpers ----------------
__device__ __forceinline__ float fast_tanh(float v) {
  float a = fabsf(v);
  float e = __expf(-2.0f * a);
  float t = __fdividef(1.0f - e, 1.0f + e);
  return copysignf(t, v);
}

__device__ __forceinline__ float dot4(float4 a, float4 b, float acc) {
  acc = fmaf(a.x, b.x, acc);
  acc = fmaf(a.y, b.y, acc);
  acc = fmaf(a.z, b.z, acc);
  acc = fmaf(a.w, b.w, acc);
  return acc;
}

__device__ __forceinline__ float wave_red64(float v) {
  #pragma unroll
  for (int off = 32; off > 0; off >>= 1) v += __shfl_xor(v, off, 64);
  return v;
}

// 4 independent 64-lane sums with 7 shuffles; lane l returns sum a_{l&3}
__device__ __forceinline__ float reduce4(float a0, float a1, float a2, float a3,
                                         bool lb0, bool lb1) {
  float uA = lb0 ? a0 : a1, kA = lb0 ? a1 : a0;
  float A = kA + __shfl_xor(uA, 1, 64);
  float uB = lb0 ? a2 : a3, kB = lb0 ? a3 : a2;
  float B = kB + __shfl_xor(uB, 1, 64);
  float uC = lb1 ? A : B, kC = lb1 ? B : A;
  float C = kC + __shfl_xor(uC, 2, 64);
  C += __shfl_xor(C, 4, 64);
  C += __shfl_xor(C, 8, 64);
  C += __shfl_xor(C, 16, 64);
  C += __shfl_xor(C, 32, 64);
  return C;
}

// device-scope (LLC-coherent) memory ops: bypass L1/L2, no cache invalidates
__device__ __forceinline__ void llc_store_f32x4(float* p, float4 v) {
  vfloat4 vv = {v.x, v.y, v.z, v.w};
  asm volatile("global_store_dwordx4 %0, %1, off sc1" :: "v"(p), "v"(vv) : "memory");
}
__device__ __forceinline__ void llc_store_u32(unsigned* p, unsigned v) {
  asm volatile("global_store_dword %0, %1, off sc1" :: "v"(p), "v"(v) : "memory");
}
__device__ __forceinline__ unsigned llc_load_u32(const unsigned* p) {
  unsigned f;
  asm volatile("global_load_dword %0, %1, off sc1\n\ts_waitcnt vmcnt(0)"
               : "=v"(f) : "v"(p) : "memory");
  return f;
}
__device__ __forceinline__ void vmcnt0() {
  asm volatile("s_waitcnt vmcnt(0)" ::: "memory");
}
// raw barriers: do NOT drain vmcnt (unlike __syncthreads)
__device__ __forceinline__ void barrier_only() {
  asm volatile("" ::: "memory");
  __builtin_amdgcn_s_barrier();
  asm volatile("" ::: "memory");
}
__device__ __forceinline__ void barrier_lgkm() {
  asm volatile("s_waitcnt lgkmcnt(0)" ::: "memory");
  __builtin_amdgcn_s_barrier();
  asm volatile("" ::: "memory");
}

// ---------------- persistent fused scan (merged L0+L1 phase) ----------------
// = round-15 kernel (session best, 11.48 ms) with ONE change: res padded to
// stride 20 (80B rows, still 16B-aligned) to break the 4-way LDS bank alias
// seen as SQ_LDS_BANK_CONFLICT=3.35e7 in r15's profile.
// Protocol: sc1 LLC state exchange, per-block flags, wave0-only poll
// (one poller per block — r16/r18 proved all-wave polling costs ~3ms),
// coarse packed publishes, 3 raw barriers/round, unroll-x2 compile-time slot.
// 4 groups x 64 blocks x 512 threads (8 waves, 88KB LDS -> 1 block/CU).
__global__ void __launch_bounds__(512, 2) esn_scan_kernel(
    const float* __restrict__ x,
    const float* __restrict__ b0,
    const float* __restrict__ b1,
    float* __restrict__ wsf,
    float* __restrict__ out) {
  __shared__ float s0l[2][4][1024];  // s0 LDS ring: slot r&1 = s0(r-1)
  __shared__ float s1l[4][1024];     // s1(r-2)
  __shared__ __align__(16) float res[2][4][20];  // stride 20: bank-spread
  extern __shared__ float dyn_pad[]; // 40KB occupancy limiter (never touched)
  if (blockIdx.x == 0x7fffffffu) dyn_pad[0] = 1.0f;  // defeat DCE, never runs

  const float* wtHH0 = wsf + OFF_WT_HH0;
  const float* wtIN1 = wsf + OFF_WT_IN1;
  const float* wtHH1 = wsf + OFF_WT_HH1;
  const float* wtIN0 = wsf + OFF_WT_IN0;
  const float* rt    = wsf + OFF_RT;
  float* s0g = wsf + OFF_S0G;
  float* s1g = wsf + OFF_S1G;
  unsigned* flags = (unsigned*)(wsf + OFF_FLAGS);

  const int tid = threadIdx.x;
  const int l = tid & 63;
  const int w = tid >> 6;            // wave 0..7
  const int bid = blockIdx.x;
  const int g = bid >> 6;            // group 0..3
  const int bg = bid & 63;           // block in group
  const int batch0 = g * 4;
  const int wg = bg * 8 + w;         // wave idx in group 0..511
  const int c0 = wg * 2;             // wave's first column (= bg*16 + w*2)
  const int wl2 = w * 2;             // block-local col base
  const bool doROw = (w >= 4);       // waves 4..7: readout (rbl=w-4, roc=bg)
  const int rbl = w - 4;             // readout local batch (RO waves)
  const int rb = batch0 + rbl;       // readout batch
  const int roc = bg;                // readout out-col
  unsigned* gflags = flags + g * 64; // [64 blocks]
  const bool lb0 = (l & 1) != 0;
  const bool lb1 = (l & 2) != 0;

  // ---- persistent per-lane weights as NAMED float4s (k = q*256 + l*4 + j) ----
  float4 wA0_0, wA0_1, wA0_2, wA0_3, wA1_0, wA1_1, wA1_2, wA1_3;
  float4 wB0_0, wB0_1, wB0_2, wB0_3, wB1_0, wB1_1, wB1_2, wB1_3;
  float4 wC0_0, wC0_1, wC0_2, wC0_3, wC1_0, wC1_1, wC1_2, wC1_3;
  float4 rd0, rd1, rd2, rd3, rd4, rd5, rd6, rd7;

#define LOADW(cc) { \
    const float* pA = wtHH0 + (size_t)(c0 + cc) * ESN_R + l * 4; \
    const float* pB = wtIN1 + (size_t)(c0 + cc) * ESN_R + l * 4; \
    const float* pC = wtHH1 + (size_t)(c0 + cc) * ESN_R + l * 4; \
    wA##cc##_0 = *(const float4*)(pA);       wA##cc##_1 = *(const float4*)(pA + 256); \
    wA##cc##_2 = *(const float4*)(pA + 512); wA##cc##_3 = *(const float4*)(pA + 768); \
    wB##cc##_0 = *(const float4*)(pB);       wB##cc##_1 = *(const float4*)(pB + 256); \
    wB##cc##_2 = *(const float4*)(pB + 512); wB##cc##_3 = *(const float4*)(pB + 768); \
    wC##cc##_0 = *(const float4*)(pC);       wC##cc##_1 = *(const float4*)(pC + 256); \
    wC##cc##_2 = *(const float4*)(pC + 512); wC##cc##_3 = *(const float4*)(pC + 768); \
  }
  LOADW(0) LOADW(1)
#undef LOADW

  rd0 = rd1 = rd2 = rd3 = rd4 = rd5 = rd6 = rd7 = make_float4(0.f, 0.f, 0.f, 0.f);
  if (doROw) {
    const float* pr = rt + (size_t)roc * 2048 + l * 4;
    rd0 = *(const float4*)(pr);        rd1 = *(const float4*)(pr + 256);
    rd2 = *(const float4*)(pr + 512);  rd3 = *(const float4*)(pr + 768);
    rd4 = *(const float4*)(pr + 1024); rd5 = *(const float4*)(pr + 1280);
    rd6 = *(const float4*)(pr + 1536); rd7 = *(const float4*)(pr + 1792);
  }
  const float wI0 = wtIN0[(size_t)(c0 + 0) * ESN_IN + l];
  const float wI1 = wtIN0[(size_t)(c0 + 1) * ESN_IN + l];
  // per-lane merged-update bias: lanes 0,1 -> b0[c0+(l&1)]; lanes 2,3 -> b1[c0+(l&1)]
  float bsel = 0.f;
  if (l < 4) bsel = ((l < 2) ? b0 : b1)[c0 + (l & 1)];

  // ---- hoisted pointers (slot-specific, selected at compile time below) ----
  const float* sA0 = s0g + 0 * NBR + batch0 * ESN_R + tid * 4;  // s0 slot0
  const float* sA1 = s0g + 1 * NBR + batch0 * ESN_R + tid * 4;  // s0 slot1
  const float* sB0 = s1g + 0 * NBR + batch0 * ESN_R + tid * 4;
  const float* sB1 = s1g + 1 * NBR + batch0 * ESN_R + tid * 4;
  // wave0 gather-store: lanes 0-15 -> s0g, lanes 16-31 -> s1g
  float* gb = ((l < 16) ? s0g : s1g) +
              (batch0 + ((l >> 2) & 3)) * ESN_R + bg * 16 + (l & 3) * 4;
  float* gbA = gb;            // slot 0
  float* gbB = gb + NBR;      // slot 1
  const float* xbase = x + (size_t)batch0 * ESN_T * ESN_IN + l;

  // One round with compile-time SLOTC (0 or 1). oslot = 1-SLOTC.
#define ESN_ROUND(SLOTC, rr)                                                   \
  {                                                                            \
    const bool doL0 = ((rr) < ESN_T);                                          \
    const bool doL1 = ((rr) >= 1 && (rr) <= ESN_T);                            \
    float xv0 = 0.f, xv1 = 0.f, xv2 = 0.f, xv3 = 0.f;                          \
    if (doL0) {                                                                \
      const float* xp = xbase + (size_t)(rr) * ESN_IN;                         \
      xv0 = xp[0 * ESN_T * ESN_IN];                                            \
      xv1 = xp[1 * ESN_T * ESN_IN];                                            \
      xv2 = xp[2 * ESN_T * ESN_IN];                                            \
      xv3 = xp[3 * ESN_T * ESN_IN];                                            \
    }                                                                          \
    if ((rr) > 0) {                                                            \
      if (w == 0) {                                                            \
        while (!__all(llc_load_u32(&gflags[l]) >= (unsigned)(rr))) {}          \
      }                                                                        \
      barrier_only(); /* syncA: release staging; LDS reuse vs prev readers */  \
    }                                                                          \
    const float* p0 = SLOTC ? sA0 : sA1; /* stage reads oslot buffers */       \
    const float* p1 = SLOTC ? sB0 : sB1;                                       \
    float4 t0, t1, u0, u1;                                                     \
    asm volatile(                                                              \
        "global_load_dwordx4 %0, %4, off sc1\n\t"                              \
        "global_load_dwordx4 %1, %5, off sc1\n\t"                              \
        "global_load_dwordx4 %2, %6, off sc1\n\t"                              \
        "global_load_dwordx4 %3, %7, off sc1\n\t"                              \
        "s_waitcnt vmcnt(0)"                                                   \
        : "=&v"(t0), "=&v"(t1), "=&v"(u0), "=&v"(u1)                           \
        : "v"(p0), "v"(p0 + 2048), "v"(p1), "v"(p1 + 2048)                     \
        : "memory");                                                           \
    {                                                                          \
      float* d0 = &s0l[SLOTC][0][0] + tid * 4;                                 \
      float* d1 = &s1l[0][0] + tid * 4;                                        \
      *(float4*)(d0)        = t0;                                              \
      *(float4*)(d0 + 2048) = t1;                                              \
      *(float4*)(d1)        = u0;                                              \
      *(float4*)(d1 + 2048) = u1;                                              \
    }                                                                          \
    barrier_lgkm(); /* syncB: s0l + s1l ready */                               \
    _Pragma("unroll")                                                          \
    for (int bb = 0; bb < 4; ++bb) {                                           \
      const float* hp = &s0l[SLOTC][bb][l * 4];                                \
      float4 h0x = *(const float4*)(hp);                                       \
      float4 h1x = *(const float4*)(hp + 256);                                 \
      float4 h2x = *(const float4*)(hp + 512);                                 \
      float4 h3x = *(const float4*)(hp + 768);                                 \
      const float* gp = &s1l[bb][l * 4];                                       \
      float4 g0x = *(const float4*)(gp);                                       \
      float4 g1x = *(const float4*)(gp + 256);                                 \
      float4 g2x = *(const float4*)(gp + 512);                                 \
      float4 g3x = *(const float4*)(gp + 768);                                 \
      float xb = (bb == 0) ? xv0 : (bb == 1) ? xv1 : (bb == 2) ? xv2 : xv3;    \
      float a0 = xb * wI0, a1 = xb * wI1;                                      \
      a0 = dot4(wA0_0, h0x, a0); a0 = dot4(wA0_1, h1x, a0);                    \
      a0 = dot4(wA0_2, h2x, a0); a0 = dot4(wA0_3, h3x, a0);                    \
      a1 = dot4(wA1_0, h0x, a1); a1 = dot4(wA1_1, h1x, a1);                    \
      a1 = dot4(wA1_2, h2x, a1); a1 = dot4(wA1_3, h3x, a1);                    \
      float a2 = 0.f, a3 = 0.f;                                                \
      a2 = dot4(wB0_0, h0x, a2); a2 = dot4(wB0_1, h1x, a2);                    \
      a2 = dot4(wB0_2, h2x, a2); a2 = dot4(wB0_3, h3x, a2);                    \
      a2 = dot4(wC0_0, g0x, a2); a2 = dot4(wC0_1, g1x, a2);                    \
      a2 = dot4(wC0_2, g2x, a2); a2 = dot4(wC0_3, g3x, a2);                    \
      a3 = dot4(wB1_0, h0x, a3); a3 = dot4(wB1_1, h1x, a3);                    \
      a3 = dot4(wB1_2, h2x, a3); a3 = dot4(wB1_3, h3x, a3);                    \
      a3 = dot4(wC1_0, g0x, a3); a3 = dot4(wC1_1, g1x, a3);                    \
      a3 = dot4(wC1_2, g2x, a3); a3 = dot4(wC1_3, g3x, a3);                    \
      float C = reduce4(a0, a1, a2, a3, lb0, lb1);                             \
      if (l < 4) { /* lanes 0,1: L0 cols; lanes 2,3: L1 cols */                \
        const float* pbase = (l < 2) ? &s0l[SLOTC][bb][0] : &s1l[bb][0];       \
        float prev = pbase[c0 + (l & 1)];                                      \
        float nv = 0.5f * prev + 0.5f * fast_tanh(C + bsel);                   \
        bool wr = (l < 2) ? doL0 : doL1;                                       \
        if (wr) res[l >> 1][bb][wl2 + (l & 1)] = nv;                           \
      }                                                                        \
    }                                                                          \
    barrier_lgkm(); /* syncD: res ready */                                     \
    if (w == 0) {                                                              \
      if (l < 32 && ((l < 16) ? doL0 : doL1)) {                                \
        float4 v;                                                              \
        {                                                                      \
          const float* rp_ = &res[l >> 4][(l >> 2) & 3][(l & 3) * 4];          \
          v = *(const float4*)rp_;                                             \
        }                                                                      \
        llc_store_f32x4(SLOTC ? gbB : gbA, v);                                 \
      }                                                                        \
      vmcnt0();                                                                \
      if (l == 0) llc_store_u32(&gflags[bg], (unsigned)((rr) + 1));            \
    }                                                                          \
    if ((rr) >= 2 && doROw) {                                                  \
      const float* sp = &s0l[1 - SLOTC][rbl][l * 4];                           \
      const float* tp = &s1l[rbl][l * 4];                                      \
      float a = 0.f;                                                           \
      a = dot4(rd0, *(const float4*)(sp), a);                                  \
      a = dot4(rd1, *(const float4*)(sp + 256), a);                            \
      a = dot4(rd2, *(const float4*)(sp + 512), a);                            \
      a = dot4(rd3, *(const float4*)(sp + 768), a);                            \
      a = dot4(rd4, *(const float4*)(tp), a);                                  \
      a = dot4(rd5, *(const float4*)(tp + 256), a);                            \
      a = dot4(rd6, *(const float4*)(tp + 512), a);                            \
      a = dot4(rd7, *(const float4*)(tp + 768), a);                            \
      a = wave_red64(a);                                                       \
      if (l == 0) out[((size_t)rb * ESN_T + ((rr) - 2)) * ESN_IN + roc] = a;   \
    }                                                                          \
  }

  // 2050 rounds = 1025 unrolled pairs; slot alternates 0,1 at compile time
  for (int rp = 0; rp < (ESN_T + 2) / 2; ++rp) {
    const int r0 = rp * 2;
    ESN_ROUND(0, r0)
    ESN_ROUND(1, r0 + 1)
  }
#undef ESN_ROUND
}

// ---------------- host launch ----------------
extern "C" void kernel_launch(void* const* d_in, const int* in_sizes, int n_in,
                              void* d_out, int out_size, void* d_ws, size_t ws_size,
                              hipStream_t stream) {
  (void)in_sizes; (void)n_in; (void)out_size; (void)ws_size;
  const float* x     = (const float*)d_in[0];
  const float* w_in0 = (const float*)d_in[1];
  const float* w_hh0 = (const float*)d_in[2];
  const float* b0    = (const float*)d_in[3];
  const float* w_in1 = (const float*)d_in[4];
  const float* w_hh1 = (const float*)d_in[5];
  const float* b1    = (const float*)d_in[6];
  const float* rdo   = (const float*)d_in[7];
  float* out = (float*)d_out;
  float* wsf = (float*)d_ws;

  dim3 tb(32, 8);
  transpose_k<<<dim3(32, 32), tb, 0, stream>>>(w_hh0, wsf + OFF_WT_HH0, 1024, 1024);
  transpose_k<<<dim3(32, 32), tb, 0, stream>>>(w_in1, wsf + OFF_WT_IN1, 1024, 1024);
  transpose_k<<<dim3(32, 32), tb, 0, stream>>>(w_hh1, wsf + OFF_WT_HH1, 1024, 1024);
  transpose_k<<<dim3(32, 2),  tb, 0, stream>>>(w_in0, wsf + OFF_WT_IN0, 64, 1024);
  transpose_k<<<dim3(2, 64),  tb, 0, stream>>>(rdo,   wsf + OFF_RT, 2048, 64);

  // zero the state slots read before first writes (r=0 reads s0g[1], s1g[1];
  // s1g[1] is read as dot-fodder before first write, so zero both s1 slots)
  (void)hipMemsetAsync(wsf + OFF_S0G + NBR, 0, NBR * sizeof(float), stream);
  (void)hipMemsetAsync(wsf + OFF_S1G, 0, 2 * NBR * sizeof(float), stream);
  (void)hipMemsetAsync(wsf + OFF_FLAGS, 0, 4 * 64 * sizeof(unsigned), stream);

  // 40KB dynamic LDS pad -> 88KB/block -> 1 block/CU; 8 waves -> 2/SIMD (TLP)
  esn_scan_kernel<<<dim3(256), dim3(512), 40960, stream>>>(x, b0, b1, wsf, out);
}